// Round 21
// baseline (366.800 us; speedup 1.0000x reference)
//
#include <hip/hip_runtime.h>
#include <hip/hip_bf16.h>
#include <cstdint>
#include <cstddef>

#define SEQ    2048
#define BATCH  2
#define HID    768
#define NH     12
#define HD     64
#define QKV_N  2304

typedef __attribute__((ext_vector_type(8))) short bf16x8;
typedef __attribute__((ext_vector_type(4))) float f32x4;
typedef __attribute__((ext_vector_type(16))) float f32x16;
typedef __attribute__((ext_vector_type(4))) unsigned int u32x4;

#define AS1C(p) ((const __attribute__((address_space(1))) void*)(p))
#define AS3(p)  ((__attribute__((address_space(3))) void*)(p))

static __device__ __forceinline__ short f2bf(float x) {
  __hip_bfloat16 h = __float2bfloat16(x);  // RNE
  short s;
  __builtin_memcpy(&s, &h, 2);
  return s;
}
static __device__ __forceinline__ float bf2f(short s) {
  __hip_bfloat16 h;
  __builtin_memcpy(&h, &s, 2);
  return __bfloat162float(h);
}
// raw v_exp_f32 (2^x), no libm slow path, no extra mul
static __device__ __forceinline__ float fast_exp2(float x) {
  return __builtin_amdgcn_exp2f(x);
}
static __device__ __forceinline__ unsigned packbf(float lo, float hi) {
  return (unsigned)(unsigned short)f2bf(lo) |
         ((unsigned)(unsigned short)f2bf(hi) << 16);
}
static __device__ __forceinline__ bf16x8 frag_from(unsigned w0, unsigned w1,
                                                   unsigned w2, unsigned w3) {
  u32x4 u = {w0, w1, w2, w3};
  bf16x8 r;
  __builtin_memcpy(&r, &u, 16);
  return r;
}

// ---------------------------------------------------------------------------
// Fused f32 -> bf16 conversion for the three inputs (one launch).
// ---------------------------------------------------------------------------
__global__ __launch_bounds__(256)
void cvt3_f32_bf16(const float* __restrict__ s0, short* __restrict__ d0,
                   const float* __restrict__ s1, short* __restrict__ d1,
                   const float* __restrict__ s2, short* __restrict__ d2) {
  int bid = blockIdx.x;
  const float* src;
  short* dst;
  if (bid < 1536)      { src = s0; dst = d0; }
  else if (bid < 2400) { src = s1; dst = d1; bid -= 1536; }
  else                 { src = s2; dst = d2; bid -= 2400; }
  const int i = (bid * 256 + threadIdx.x) * 8;
  const float4 a = *reinterpret_cast<const float4*>(src + i);
  const float4 b = *reinterpret_cast<const float4*>(src + i + 4);
  bf16x8 o;
  o[0] = f2bf(a.x); o[1] = f2bf(a.y); o[2] = f2bf(a.z); o[3] = f2bf(a.w);
  o[4] = f2bf(b.x); o[5] = f2bf(b.y); o[6] = f2bf(b.z); o[7] = f2bf(b.w);
  *reinterpret_cast<bf16x8*>(dst + i) = o;
}

// ---------------------------------------------------------------------------
// QKV GEMM, 128x96 tiles (768 blocks = 3/CU), V written transposed directly
// to vtg. Round-18 verified, UNCHANGED.
// ---------------------------------------------------------------------------
__global__ __launch_bounds__(256)
void gemm_qkv(const short* __restrict__ A, const short* __restrict__ B,
              short* __restrict__ C, short* __restrict__ vtg) {
  const int K = HID, N = QKV_N;
  __shared__ short As[128][64];   // 16 KB
  __shared__ short Bs[96][64];    // 12 KB

  const int t = threadIdx.x;
  const int w = t >> 6;
  const int l = t & 63;
  const int g = l >> 4;
  const int n = l & 15;

  const int m0 = blockIdx.y * 128;
  const int n0 = blockIdx.x * 96;
  const int wr = (w >> 1) * 64;
  const int wc = (w & 1) * 48;

  const int srowA = w * 32 + (l >> 3);
  const int srowB = w * 24 + (l >> 3);
  const int scol  = (l & 7) * 8;
  const short* Ag = A + (size_t)(m0 + srowA) * K + scol;
  const short* Bg = B + (size_t)(n0 + srowB) * K + scol;

  f32x4 acc[4][3] = {};

  for (int k0 = 0; k0 < K; k0 += 64) {
    __syncthreads();
#pragma unroll
    for (int it = 0; it < 4; ++it) {
      __builtin_amdgcn_global_load_lds(AS1C(Ag + (size_t)(it * 8) * K + k0),
                                       AS3(&As[w * 32 + it * 8][0]), 16, 0, 0);
    }
#pragma unroll
    for (int it = 0; it < 3; ++it) {
      __builtin_amdgcn_global_load_lds(AS1C(Bg + (size_t)(it * 8) * K + k0),
                                       AS3(&Bs[w * 24 + it * 8][0]), 16, 0, 0);
    }
    __syncthreads();

#pragma unroll
    for (int kk = 0; kk < 2; ++kk) {
      bf16x8 af[4], bfr[3];
#pragma unroll
      for (int m = 0; m < 4; ++m)
        af[m] = *reinterpret_cast<const bf16x8*>(&As[wr + m * 16 + n][kk * 32 + g * 8]);
#pragma unroll
      for (int j = 0; j < 3; ++j)
        bfr[j] = *reinterpret_cast<const bf16x8*>(&Bs[wc + j * 16 + n][kk * 32 + g * 8]);
#pragma unroll
      for (int m = 0; m < 4; ++m)
#pragma unroll
        for (int j = 0; j < 3; ++j)
          acc[m][j] = __builtin_amdgcn_mfma_f32_16x16x32_bf16(af[m], bfr[j], acc[m][j], 0, 0, 0);
    }
  }

  if (n0 < 1536) {
    // ---- Q/K region: bf16 scalar stores to qkvb ----
#pragma unroll
    for (int m = 0; m < 4; ++m) {
#pragma unroll
      for (int r = 0; r < 4; ++r) {
        const size_t row = m0 + wr + m * 16 + g * 4 + r;
#pragma unroll
        for (int j = 0; j < 3; ++j) {
          const int col = n0 + wc + j * 16 + n;
          C[row * N + col] = f2bf(acc[m][j][r]);
        }
      }
    }
  } else {
    // ---- V region: write transposed directly into vtg ----
    const int b = m0 >> 11;              // batch (uniform per tile)
#pragma unroll
    for (int m = 0; m < 4; ++m) {
      const int kvbase = (m0 & 2047) + wr + m * 16 + g * 4;   // % 4 == 0
#pragma unroll
      for (int j = 0; j < 3; ++j) {
        const int col2 = n0 - 1536 + wc + j * 16 + n;
        const int h = col2 >> 6;
        const int d = col2 & 63;
        short4 pk;
        pk.x = f2bf(acc[m][j][0]);
        pk.y = f2bf(acc[m][j][1]);
        pk.z = f2bf(acc[m][j][2]);
        pk.w = f2bf(acc[m][j][3]);
        *reinterpret_cast<short4*>(
            &vtg[(((size_t)b * NH + h) * 64 + d) * SEQ + kvbase]) = pk;
      }
    }
  }
}

// ---------------------------------------------------------------------------
// bf16 MFMA GEMM NT, 64x64 tile — out-proj (768 blocks = 3/CU). Known-good.
// ---------------------------------------------------------------------------
__global__ __launch_bounds__(256)
void gemm_nt_mfma64(const short* __restrict__ A, const short* __restrict__ B,
                    const float* __restrict__ bias, float* __restrict__ Cf,
                    int M, int N, int K) {
  __shared__ short As[64][64];
  __shared__ short Bs[64][64];

  const int t = threadIdx.x;
  const int w = t >> 6;
  const int l = t & 63;
  const int g = l >> 4;
  const int n = l & 15;

  const int m0 = blockIdx.y * 64;
  const int n0 = blockIdx.x * 64;
  const int wr = (w >> 1) * 32;
  const int wc = (w & 1) * 32;

  const int srow = t >> 3;
  const int scol = (t & 7) * 8;
  const short* Ag = A + (size_t)(m0 + srow) * K + scol;
  const short* Bg = B + (size_t)(n0 + srow) * K + scol;

  f32x4 acc[2][2] = {};

  for (int k0 = 0; k0 < K; k0 += 64) {
    __syncthreads();
#pragma unroll
    for (int it = 0; it < 2; ++it) {
      __builtin_amdgcn_global_load_lds(AS1C(Ag + (size_t)(it * 32) * K + k0),
                                       AS3(&As[w * 8 + it * 32][0]), 16, 0, 0);
    }
#pragma unroll
    for (int it = 0; it < 2; ++it) {
      __builtin_amdgcn_global_load_lds(AS1C(Bg + (size_t)(it * 32) * K + k0),
                                       AS3(&Bs[w * 8 + it * 32][0]), 16, 0, 0);
    }
    __syncthreads();

#pragma unroll
    for (int kk = 0; kk < 2; ++kk) {
      bf16x8 af[2], bfr[2];
#pragma unroll
      for (int m = 0; m < 2; ++m)
        af[m] = *reinterpret_cast<const bf16x8*>(&As[wr + m * 16 + n][kk * 32 + g * 8]);
#pragma unroll
      for (int j = 0; j < 2; ++j)
        bfr[j] = *reinterpret_cast<const bf16x8*>(&Bs[wc + j * 16 + n][kk * 32 + g * 8]);
#pragma unroll
      for (int m = 0; m < 2; ++m)
#pragma unroll
        for (int j = 0; j < 2; ++j)
          acc[m][j] = __builtin_amdgcn_mfma_f32_16x16x32_bf16(af[m], bfr[j], acc[m][j], 0, 0, 0);
    }
  }

#pragma unroll
  for (int m = 0; m < 2; ++m) {
#pragma unroll
    for (int r = 0; r < 4; ++r) {
      const size_t row = m0 + wr + m * 16 + g * 4 + r;
#pragma unroll
      for (int j = 0; j < 2; ++j) {
        const int col = n0 + wc + j * 16 + n;
        Cf[row * N + col] = acc[m][j][r] + bias[col];
      }
    }
  }
}

// ---------------------------------------------------------------------------
// Flash attention, 32x32x16 MFMA — round-18 structure with P IN-REGISTER:
// the Ps LDS buffer (20 KB) is deleted; PV B-fragments are assembled from
// packed bf16 words exchanged between lanes l and l^32 via __shfl_xor(.,32)
// (primitive verified in-session since r4). Derivation: fragment c needs
// P[y=c*16+hi*8+u][q31]; lane (q31,hi) owns e[rr*4+j]=P[rr*8+hi*4+j], so
// frag = own W[c*2+hi] pair + partner's same-rr pair. mrow is pair-uniform
// (pm is pair-maxed before the defer branch), so exchanged values share m.
// LDS: K 16K + V 16K = 32K loop (+ merge buffer 34,816) -> 36,864 B total
// -> 4 blocks/CU (32 waves) when VGPR <= 64; __launch_bounds__(512,8)
// pins the allocator there.
// ---------------------------------------------------------------------------
__global__ __launch_bounds__(512, 8)
void attn_mfma(const short* __restrict__ qkv, const short* __restrict__ vtg,
               short* __restrict__ att) {
  const int bh = blockIdx.x;           // 0..23
  const int qt = blockIdx.y;           // 0..31
  const int b  = bh / NH;
  const int h0 = bh % NH;
  const int q0 = qt * 64;

  const int t   = threadIdx.x;
  const int w   = t >> 6;              // wave 0..7
  const int l   = t & 63;
  const int hi  = l >> 5;              // k-half
  const int q31 = l & 31;              // q column owned by this lane
  const int qq  = w >> 2;              // q 32-row group
  const int kh  = w & 3;               // kv quarter

  __shared__ __align__(16) char smem[36864];
  short* KxL = (short*)smem;            // [128][64] linear, 16384 B
  short* VxL = (short*)(smem + 16384);  // [64][128] swizzled, 16384 B

  const short* baseq = qkv + (size_t)b * SEQ * QKV_N + h0 * HD;
  const short* Kg    = baseq + HID;
  const short* vt_bh = vtg + (size_t)bh * 64 * SEQ;

  // ---- Q B-fragments, pre-scaled by 0.125 * log2(e) (scores in log2) ----
  bf16x8 qf[4];
  {
    const short* qrow = baseq + (size_t)(q0 + qq * 32 + q31) * QKV_N;
#pragma unroll
    for (int c16 = 0; c16 < 4; ++c16) {
      bf16x8 raw = *reinterpret_cast<const bf16x8*>(qrow + c16 * 16 + hi * 8);
#pragma unroll
      for (int j = 0; j < 8; ++j)
        qf[c16][j] = f2bf(bf2f(raw[j]) * 0.1803368801f);
    }
  }

  f32x16 o0 = {};
  f32x16 o1 = {};
  float mrow = -3e38f;
  float lrow = 0.f;

  // ---- K DMA source indices (per thread, 2 instrs; r9-verified) ----
  const int kv0  = t >> 3;
  const int dg0  = (t & 7) ^ (kv0 & 7);
  const int kv1  = kv0 + 64;
  const int dg1  = (t & 7) ^ (kv1 & 7);
  const short* ks0 = Kg + (size_t)kv0 * QKV_N + dg0 * 8;
  const short* ks1 = Kg + (size_t)kv1 * QKV_N + dg1 * 8;

  // ---- V reg-load sources (LINEAR granule: coalesced 256 B rows) and
  //      ds_write destinations (XOR'd granule -> r14-identical layout) ----
  const int vd0  = t >> 4;             // d row 0..31
  const int vd1  = vd0 + 32;
  const short* vls0 = vt_bh + (size_t)vd0 * SEQ + (t & 15) * 8;
  const short* vls1 = vt_bh + (size_t)vd1 * SEQ + (t & 15) * 8;
  short* vwd0 = VxL + vd0 * 128 + (((t & 15) ^ (vd0 & 15)) * 8);
  short* vwd1 = VxL + vd1 * 128 + (((t & 15) ^ (vd1 & 15)) * 8);
  // prologue V(0) DMA (r14-verified source permute, dest lane-linear):
  const short* vs0 = vt_bh + (size_t)vd0 * SEQ + (((t & 15) ^ (vd0 & 15)) * 8);
  const short* vs1 = vt_bh + (size_t)vd1 * SEQ + (((t & 15) ^ (vd1 & 15)) * 8);

  // ---- prologue: DMA K(0), V(0); drain at barrier ----
  __builtin_amdgcn_global_load_lds(AS1C(ks0), AS3(KxL + w * 512), 16, 0, 0);
  __builtin_amdgcn_global_load_lds(AS1C(ks1), AS3(KxL + w * 512 + 4096), 16, 0, 0);
  __builtin_amdgcn_global_load_lds(AS1C(vs0), AS3(VxL + w * 512), 16, 0, 0);
  __builtin_amdgcn_global_load_lds(AS1C(vs1), AS3(VxL + w * 512 + 4096), 16, 0, 0);
  __syncthreads();

  const int krow = kh * 32 + q31;
  const int kxor = l & 7;
  const int vx0  = q31 & 15;           // V read-side granule XOR (d & 15)

  for (int ti = 0; ti < SEQ / 128; ++ti) {
    const bool have_next = (ti + 1) < SEQ / 128;

    // ---- QK^T(ti): 4 b128 K reads + 4 MFMA ----
    f32x16 sc = {};
#pragma unroll
    for (int c16 = 0; c16 < 4; ++c16) {
      bf16x8 kb = *reinterpret_cast<const bf16x8*>(
          (const char*)KxL + krow * 128 + (((c16 * 2 + hi) ^ kxor) << 4));
      sc = __builtin_amdgcn_mfma_f32_32x32x16_bf16(kb, qf[c16], sc, 0, 0, 0);
    }
    __syncthreads();   // BAR-A: QK reads retired (Kx free); drains prior
                       //        iteration's V ds_writes (lgkmcnt, cheap)

    // ---- issue K(ti+1) DMA + V(ti+1) reg loads (both drain at BAR-B;
    //      in-flight window = softmax + PV ≈ 500 cy) ----
    bf16x8 vA, vB;
    if (have_next) {
      const size_t rb = (size_t)(ti + 1) * 128 * QKV_N;
      __builtin_amdgcn_global_load_lds(AS1C(ks0 + rb), AS3(KxL + w * 512), 16, 0, 0);
      __builtin_amdgcn_global_load_lds(AS1C(ks1 + rb), AS3(KxL + w * 512 + 4096), 16, 0, 0);
      const size_t vb = (size_t)(ti + 1) * 128;
      vA = *reinterpret_cast<const bf16x8*>(vls0 + vb);
      vB = *reinterpret_cast<const bf16x8*>(vls1 + vb);
    }

    // ---- softmax(ti) + PV(ti), P in-register (log2 domain) ----
    {
      float pm = fmaxf(fmaxf(sc[0], sc[1]), fmaxf(sc[2], sc[3]));
#pragma unroll
      for (int r = 4; r < 16; r += 4)
        pm = fmaxf(pm, fmaxf(fmaxf(sc[r], sc[r + 1]), fmaxf(sc[r + 2], sc[r + 3])));
      pm = fmaxf(pm, __shfl_xor(pm, 32));   // pair-uniform max
      if (__any(pm - mrow > 8.f)) {         // defer-max (THR=8), wave-uniform
        const float mnew = fmaxf(mrow, pm);
        const float corr = fast_exp2(mrow - mnew);
        mrow = mnew;
        lrow *= corr;
#pragma unroll
        for (int r = 0; r < 16; ++r) { o0[r] *= corr; o1[r] *= corr; }
      }
      float psum = 0.f;
#pragma unroll
      for (int c = 0; c < 2; ++c) {
        const int rr0 = c * 2, rr1 = c * 2 + 1;
        const float e0 = fast_exp2(sc[rr0 * 4 + 0] - mrow);
        const float e1 = fast_exp2(sc[rr0 * 4 + 1] - mrow);
        const float e2 = fast_exp2(sc[rr0 * 4 + 2] - mrow);
        const float e3 = fast_exp2(sc[rr0 * 4 + 3] - mrow);
        const float e4 = fast_exp2(sc[rr1 * 4 + 0] - mrow);
        const float e5 = fast_exp2(sc[rr1 * 4 + 1] - mrow);
        const float e6 = fast_exp2(sc[rr1 * 4 + 2] - mrow);
        const float e7 = fast_exp2(sc[rr1 * 4 + 3] - mrow);
        psum += ((e0 + e1) + (e2 + e3)) + ((e4 + e5) + (e6 + e7));
        const unsigned W0 = packbf(e0, e1), W1 = packbf(e2, e3);   // rr = c*2
        const unsigned W2 = packbf(e4, e5), W3 = packbf(e6, e7);   // rr = c*2+1
        // exchange: lane hi=0 sends W[c*2+1] (W2,W3), receives partner W[c*2];
        //           lane hi=1 sends W[c*2] (W0,W1), receives partner W[c*2+1].
        const unsigned s0 = hi ? W0 : W2;
        const unsigned s1 = hi ? W1 : W3;
        const unsigned r0 = __shfl_xor(s0, 32);
        const unsigned r1 = __shfl_xor(s1, 32);
        const unsigned a0 = hi ? r0 : W0;
        const unsigned a1 = hi ? r1 : W1;
        const unsigned a2 = hi ? W2 : r0;
        const unsigned a3 = hi ? W3 : r1;
        bf16x8 pb = frag_from(a0, a1, a2, a3);
        const int kvg = kh * 4 + c * 2 + hi;
        {
          bf16x8 va = *reinterpret_cast<const bf16x8*>(
              (const char*)VxL + q31 * 256 + ((kvg ^ vx0) << 4));
          o0 = __builtin_amdgcn_mfma_f32_32x32x16_bf16(va, pb, o0, 0, 0, 0);
        }
        {
          bf16x8 va = *reinterpret_cast<const bf16x8*>(
              (const char*)VxL + (32 + q31) * 256 + ((kvg ^ vx0) << 4));
          o1 = __builtin_amdgcn_mfma_f32_32x32x16_bf16(va, pb, o1, 0, 0, 0);
        }
      }
      lrow += psum;
    }
    __syncthreads();   // BAR-B: PV reads retired; drains K(ti+1) DMA and
                       //        the V(ti+1) reg loads (vmcnt(0))

    // ---- write V(ti+1) regs -> VxL (safe: PV(ti) reads retired; ordered
    //      before PV(ti+1) by BAR-A(ti+1)'s lgkmcnt) ----
    if (have_next) {
      *reinterpret_cast<bf16x8*>(vwd0) = vA;
      *reinterpret_cast<bf16x8*>(vwd1) = vB;
    }
  }

  // ---- combine the two k-half l partials (lanes l, l^32 share q) ----
  lrow += __shfl_xor(lrow, 32);

  // ---- exact flash merge of the 4 kh partials (r12-verified; log2 dom) ----
  float* mbf = (float*)smem;           // 34 f32 x 64 lanes x 4 slots = 34,816 B
  const int base = (qq * 2 + (kh >> 1)) * 2176 + l * 34;
  if (kh & 1) {                        // kh = 1,3 write
#pragma unroll
    for (int r = 0; r < 16; ++r) { mbf[base + r] = o0[r]; mbf[base + 16 + r] = o1[r]; }
    mbf[base + 32] = mrow;
    mbf[base + 33] = lrow;
  }
  __syncthreads();
  if (!(kh & 1)) {                     // kh = 0,2 merge partner kh+1
    const float m2 = mbf[base + 32];
    const float l2 = mbf[base + 33];
    const float mn = fmaxf(mrow, m2);
    const float ca = fast_exp2(mrow - mn);
    const float cb = fast_exp2(m2 - mn);
#pragma unroll
    for (int r = 0; r < 16; ++r) {
      o0[r] = o0[r] * ca + mbf[base + r] * cb;
      o1[r] = o1[r] * ca + mbf[base + 16 + r] * cb;
    }
    lrow = lrow * ca + l2 * cb;
    mrow = mn;
  }
  __syncthreads();
  const int base2 = qq * 2176 + l * 34;
  if (kh == 2) {                       // merged (2,3) -> slot qq
#pragma unroll
    for (int r = 0; r < 16; ++r) { mbf[base2 + r] = o0[r]; mbf[base2 + 16 + r] = o1[r]; }
    mbf[base2 + 32] = mrow;
    mbf[base2 + 33] = lrow;
  }
  __syncthreads();
  if (kh == 0) {                       // final merge + normalize + store
    const float m2 = mbf[base2 + 32];
    const float l2 = mbf[base2 + 33];
    const float mn = fmaxf(mrow, m2);
    const float ca = fast_exp2(mrow - mn);
    const float cb = fast_exp2(m2 - mn);
    const float lm = lrow * ca + l2 * cb;
    const float linv = 1.f / lm;
    short* orow = att + (size_t)(b * SEQ + q0 + qq * 32 + q31) * HID + h0 * HD;
#pragma unroll
    for (int rr = 0; rr < 4; ++rr) {
      short4 ov;
      ov.x = f2bf((o0[rr * 4 + 0] * ca + mbf[base2 + rr * 4 + 0] * cb) * linv);
      ov.y = f2bf((o0[rr * 4 + 1] * ca + mbf[base2 + rr * 4 + 1] * cb) * linv);
      ov.z = f2bf((o0[rr * 4 + 2] * ca + mbf[base2 + rr * 4 + 2] * cb) * linv);
      ov.w = f2bf((o0[rr * 4 + 3] * ca + mbf[base2 + rr * 4 + 3] * cb) * linv);
      *reinterpret_cast<short4*>(&orow[rr * 8 + hi * 4]) = ov;
      short4 ow;
      ow.x = f2bf((o1[rr * 4 + 0] * ca + mbf[base2 + 16 + rr * 4 + 0] * cb) * linv);
      ow.y = f2bf((o1[rr * 4 + 1] * ca + mbf[base2 + 16 + rr * 4 + 1] * cb) * linv);
      ow.z = f2bf((o1[rr * 4 + 2] * ca + mbf[base2 + 16 + rr * 4 + 2] * cb) * linv);
      ow.w = f2bf((o1[rr * 4 + 3] * ca + mbf[base2 + 16 + rr * 4 + 3] * cb) * linv);
      *reinterpret_cast<short4*>(&orow[32 + rr * 8 + hi * 4]) = ow;
    }
  }
}

// ---------------------------------------------------------------------------
extern "C" void kernel_launch(void* const* d_in, const int* in_sizes, int n_in,
                              void* d_out, int out_size, void* d_ws, size_t ws_size,
                              hipStream_t stream) {
  const float* x     = (const float*)d_in[0];  // [2,2048,768]
  const float* w_qkv = (const float*)d_in[1];  // [2304,768]
  const float* w_out = (const float*)d_in[2];  // [768,768]
  const float* b_out = (const float*)d_in[3];  // [768]
  float* out = (float*)d_out;                  // [2,2048,768]

  const int NX  = BATCH * SEQ * HID;   // 3,145,728
  const int NWQ = QKV_N * HID;         // 1,769,472
  const int NWO = HID * HID;           //   589,824

  char* ws = (char*)d_ws;
  short* xb   = (short*)ws;  ws += (size_t)NX  * 2;
  short* wqb  = (short*)ws;  ws += (size_t)NWQ * 2;
  short* wob  = (short*)ws;  ws += (size_t)NWO * 2;
  short* qkvb = (short*)ws;  ws += (size_t)BATCH * SEQ * QKV_N * 2;
  short* attb = (short*)ws;  ws += (size_t)BATCH * SEQ * HID * 2;
  short* vtg  = (short*)ws;  // [24][64][2048] bf16 = 6 MB

  cvt3_f32_bf16<<<dim3(2688), dim3(256), 0, stream>>>(x, xb, w_qkv, wqb, w_out, wob);

  // QKV projection (128x96 tiles; V written transposed directly to vtg)
  gemm_qkv<<<dim3(QKV_N / 96, (BATCH * SEQ) / 128), dim3(256), 0, stream>>>(
      xb, wqb, qkvb, vtg);

  // bf16 MFMA flash attention (in-register P via shfl_xor; Ps deleted)
  attn_mfma<<<dim3(BATCH * NH, SEQ / 64), dim3(512), 0, stream>>>(qkvb, vtg, attb);

  // out projection (64x64 tiles -> 768 blocks = 3/CU)
  gemm_nt_mfma64<<<dim3(HID / 64, (BATCH * SEQ) / 64), dim3(256), 0, stream>>>(
      attb, wob, b_out, out, BATCH * SEQ, HID, HID);
}

// Round 22
// 96.909 us; speedup vs baseline: 3.7850x; 3.7850x over previous
//
#include <hip/hip_runtime.h>
#include <hip/hip_bf16.h>
#include <cstdint>
#include <cstddef>

#define SEQ    2048
#define BATCH  2
#define HID    768
#define NH     12
#define HD     64
#define QKV_N  2304

typedef __attribute__((ext_vector_type(8))) short bf16x8;
typedef __attribute__((ext_vector_type(4))) float f32x4;
typedef __attribute__((ext_vector_type(16))) float f32x16;
typedef __attribute__((ext_vector_type(4))) unsigned int u32x4;

#define AS1C(p) ((const __attribute__((address_space(1))) void*)(p))
#define AS3(p)  ((__attribute__((address_space(3))) void*)(p))

static __device__ __forceinline__ short f2bf(float x) {
  __hip_bfloat16 h = __float2bfloat16(x);  // RNE
  short s;
  __builtin_memcpy(&s, &h, 2);
  return s;
}
static __device__ __forceinline__ float bf2f(short s) {
  __hip_bfloat16 h;
  __builtin_memcpy(&h, &s, 2);
  return __bfloat162float(h);
}
// raw v_exp_f32 (2^x), no libm slow path, no extra mul
static __device__ __forceinline__ float fast_exp2(float x) {
  return __builtin_amdgcn_exp2f(x);
}
static __device__ __forceinline__ unsigned packbf(float lo, float hi) {
  return (unsigned)(unsigned short)f2bf(lo) |
         ((unsigned)(unsigned short)f2bf(hi) << 16);
}
static __device__ __forceinline__ bf16x8 frag_from(unsigned w0, unsigned w1,
                                                   unsigned w2, unsigned w3) {
  u32x4 u = {w0, w1, w2, w3};
  bf16x8 r;
  __builtin_memcpy(&r, &u, 16);
  return r;
}

// ---------------------------------------------------------------------------
// Fused f32 -> bf16 conversion for the three inputs (one launch).
// ---------------------------------------------------------------------------
__global__ __launch_bounds__(256)
void cvt3_f32_bf16(const float* __restrict__ s0, short* __restrict__ d0,
                   const float* __restrict__ s1, short* __restrict__ d1,
                   const float* __restrict__ s2, short* __restrict__ d2) {
  int bid = blockIdx.x;
  const float* src;
  short* dst;
  if (bid < 1536)      { src = s0; dst = d0; }
  else if (bid < 2400) { src = s1; dst = d1; bid -= 1536; }
  else                 { src = s2; dst = d2; bid -= 2400; }
  const int i = (bid * 256 + threadIdx.x) * 8;
  const float4 a = *reinterpret_cast<const float4*>(src + i);
  const float4 b = *reinterpret_cast<const float4*>(src + i + 4);
  bf16x8 o;
  o[0] = f2bf(a.x); o[1] = f2bf(a.y); o[2] = f2bf(a.z); o[3] = f2bf(a.w);
  o[4] = f2bf(b.x); o[5] = f2bf(b.y); o[6] = f2bf(b.z); o[7] = f2bf(b.w);
  *reinterpret_cast<bf16x8*>(dst + i) = o;
}

// ---------------------------------------------------------------------------
// QKV GEMM, 128x96 tiles (768 blocks = 3/CU), V written transposed directly
// to vtg. Round-18 verified, UNCHANGED.
// ---------------------------------------------------------------------------
__global__ __launch_bounds__(256)
void gemm_qkv(const short* __restrict__ A, const short* __restrict__ B,
              short* __restrict__ C, short* __restrict__ vtg) {
  const int K = HID, N = QKV_N;
  __shared__ short As[128][64];   // 16 KB
  __shared__ short Bs[96][64];    // 12 KB

  const int t = threadIdx.x;
  const int w = t >> 6;
  const int l = t & 63;
  const int g = l >> 4;
  const int n = l & 15;

  const int m0 = blockIdx.y * 128;
  const int n0 = blockIdx.x * 96;
  const int wr = (w >> 1) * 64;
  const int wc = (w & 1) * 48;

  const int srowA = w * 32 + (l >> 3);
  const int srowB = w * 24 + (l >> 3);
  const int scol  = (l & 7) * 8;
  const short* Ag = A + (size_t)(m0 + srowA) * K + scol;
  const short* Bg = B + (size_t)(n0 + srowB) * K + scol;

  f32x4 acc[4][3] = {};

  for (int k0 = 0; k0 < K; k0 += 64) {
    __syncthreads();
#pragma unroll
    for (int it = 0; it < 4; ++it) {
      __builtin_amdgcn_global_load_lds(AS1C(Ag + (size_t)(it * 8) * K + k0),
                                       AS3(&As[w * 32 + it * 8][0]), 16, 0, 0);
    }
#pragma unroll
    for (int it = 0; it < 3; ++it) {
      __builtin_amdgcn_global_load_lds(AS1C(Bg + (size_t)(it * 8) * K + k0),
                                       AS3(&Bs[w * 24 + it * 8][0]), 16, 0, 0);
    }
    __syncthreads();

#pragma unroll
    for (int kk = 0; kk < 2; ++kk) {
      bf16x8 af[4], bfr[3];
#pragma unroll
      for (int m = 0; m < 4; ++m)
        af[m] = *reinterpret_cast<const bf16x8*>(&As[wr + m * 16 + n][kk * 32 + g * 8]);
#pragma unroll
      for (int j = 0; j < 3; ++j)
        bfr[j] = *reinterpret_cast<const bf16x8*>(&Bs[wc + j * 16 + n][kk * 32 + g * 8]);
#pragma unroll
      for (int m = 0; m < 4; ++m)
#pragma unroll
        for (int j = 0; j < 3; ++j)
          acc[m][j] = __builtin_amdgcn_mfma_f32_16x16x32_bf16(af[m], bfr[j], acc[m][j], 0, 0, 0);
    }
  }

  if (n0 < 1536) {
    // ---- Q/K region: bf16 scalar stores to qkvb ----
#pragma unroll
    for (int m = 0; m < 4; ++m) {
#pragma unroll
      for (int r = 0; r < 4; ++r) {
        const size_t row = m0 + wr + m * 16 + g * 4 + r;
#pragma unroll
        for (int j = 0; j < 3; ++j) {
          const int col = n0 + wc + j * 16 + n;
          C[row * N + col] = f2bf(acc[m][j][r]);
        }
      }
    }
  } else {
    // ---- V region: write transposed directly into vtg ----
    const int b = m0 >> 11;              // batch (uniform per tile)
#pragma unroll
    for (int m = 0; m < 4; ++m) {
      const int kvbase = (m0 & 2047) + wr + m * 16 + g * 4;   // % 4 == 0
#pragma unroll
      for (int j = 0; j < 3; ++j) {
        const int col2 = n0 - 1536 + wc + j * 16 + n;
        const int h = col2 >> 6;
        const int d = col2 & 63;
        short4 pk;
        pk.x = f2bf(acc[m][j][0]);
        pk.y = f2bf(acc[m][j][1]);
        pk.z = f2bf(acc[m][j][2]);
        pk.w = f2bf(acc[m][j][3]);
        *reinterpret_cast<short4*>(
            &vtg[(((size_t)b * NH + h) * 64 + d) * SEQ + kvbase]) = pk;
      }
    }
  }
}

// ---------------------------------------------------------------------------
// bf16 MFMA GEMM NT, 64x64 tile — out-proj (768 blocks = 3/CU). Known-good.
// ---------------------------------------------------------------------------
__global__ __launch_bounds__(256)
void gemm_nt_mfma64(const short* __restrict__ A, const short* __restrict__ B,
                    const float* __restrict__ bias, float* __restrict__ Cf,
                    int M, int N, int K) {
  __shared__ short As[64][64];
  __shared__ short Bs[64][64];

  const int t = threadIdx.x;
  const int w = t >> 6;
  const int l = t & 63;
  const int g = l >> 4;
  const int n = l & 15;

  const int m0 = blockIdx.y * 64;
  const int n0 = blockIdx.x * 64;
  const int wr = (w >> 1) * 32;
  const int wc = (w & 1) * 32;

  const int srow = t >> 3;
  const int scol = (t & 7) * 8;
  const short* Ag = A + (size_t)(m0 + srow) * K + scol;
  const short* Bg = B + (size_t)(n0 + srow) * K + scol;

  f32x4 acc[2][2] = {};

  for (int k0 = 0; k0 < K; k0 += 64) {
    __syncthreads();
#pragma unroll
    for (int it = 0; it < 2; ++it) {
      __builtin_amdgcn_global_load_lds(AS1C(Ag + (size_t)(it * 32) * K + k0),
                                       AS3(&As[w * 8 + it * 32][0]), 16, 0, 0);
    }
#pragma unroll
    for (int it = 0; it < 2; ++it) {
      __builtin_amdgcn_global_load_lds(AS1C(Bg + (size_t)(it * 32) * K + k0),
                                       AS3(&Bs[w * 8 + it * 32][0]), 16, 0, 0);
    }
    __syncthreads();

#pragma unroll
    for (int kk = 0; kk < 2; ++kk) {
      bf16x8 af[2], bfr[2];
#pragma unroll
      for (int m = 0; m < 2; ++m)
        af[m] = *reinterpret_cast<const bf16x8*>(&As[wr + m * 16 + n][kk * 32 + g * 8]);
#pragma unroll
      for (int j = 0; j < 2; ++j)
        bfr[j] = *reinterpret_cast<const bf16x8*>(&Bs[wc + j * 16 + n][kk * 32 + g * 8]);
#pragma unroll
      for (int m = 0; m < 2; ++m)
#pragma unroll
        for (int j = 0; j < 2; ++j)
          acc[m][j] = __builtin_amdgcn_mfma_f32_16x16x32_bf16(af[m], bfr[j], acc[m][j], 0, 0, 0);
    }
  }

#pragma unroll
  for (int m = 0; m < 2; ++m) {
#pragma unroll
    for (int r = 0; r < 4; ++r) {
      const size_t row = m0 + wr + m * 16 + g * 4 + r;
#pragma unroll
      for (int j = 0; j < 2; ++j) {
        const int col = n0 + wc + j * 16 + n;
        Cf[row * N + col] = acc[m][j][r] + bias[col];
      }
    }
  }
}

// ---------------------------------------------------------------------------
// Flash attention, 32x32x16 MFMA — in-register P (r21-verified-correct),
// launch bounds FIXED: __launch_bounds__(512) (no waves/EU pin). r21's
// (512,8) clamped the allocator to 32 VGPR -> o0/o1 spilled to scratch
// (748 MB writes, 337 us). Natural allocation ~64-80 VGPR, no spills;
// LDS 36,864 B -> 3-4 blocks/CU.
// P exchange: frag c = own W[c*2+hi] pair + partner(l^32) same-rr pair via
// __shfl_xor(.,32); mrow pair-uniform. Ps LDS buffer deleted.
// ---------------------------------------------------------------------------
__global__ __launch_bounds__(512)
void attn_mfma(const short* __restrict__ qkv, const short* __restrict__ vtg,
               short* __restrict__ att) {
  const int bh = blockIdx.x;           // 0..23
  const int qt = blockIdx.y;           // 0..31
  const int b  = bh / NH;
  const int h0 = bh % NH;
  const int q0 = qt * 64;

  const int t   = threadIdx.x;
  const int w   = t >> 6;              // wave 0..7
  const int l   = t & 63;
  const int hi  = l >> 5;              // k-half
  const int q31 = l & 31;              // q column owned by this lane
  const int qq  = w >> 2;              // q 32-row group
  const int kh  = w & 3;               // kv quarter

  __shared__ __align__(16) char smem[36864];
  short* KxL = (short*)smem;            // [128][64] linear, 16384 B
  short* VxL = (short*)(smem + 16384);  // [64][128] swizzled, 16384 B

  const short* baseq = qkv + (size_t)b * SEQ * QKV_N + h0 * HD;
  const short* Kg    = baseq + HID;
  const short* vt_bh = vtg + (size_t)bh * 64 * SEQ;

  // ---- Q B-fragments, pre-scaled by 0.125 * log2(e) (scores in log2) ----
  bf16x8 qf[4];
  {
    const short* qrow = baseq + (size_t)(q0 + qq * 32 + q31) * QKV_N;
#pragma unroll
    for (int c16 = 0; c16 < 4; ++c16) {
      bf16x8 raw = *reinterpret_cast<const bf16x8*>(qrow + c16 * 16 + hi * 8);
#pragma unroll
      for (int j = 0; j < 8; ++j)
        qf[c16][j] = f2bf(bf2f(raw[j]) * 0.1803368801f);
    }
  }

  f32x16 o0 = {};
  f32x16 o1 = {};
  float mrow = -3e38f;
  float lrow = 0.f;

  // ---- K DMA source indices (per thread, 2 instrs; r9-verified) ----
  const int kv0  = t >> 3;
  const int dg0  = (t & 7) ^ (kv0 & 7);
  const int kv1  = kv0 + 64;
  const int dg1  = (t & 7) ^ (kv1 & 7);
  const short* ks0 = Kg + (size_t)kv0 * QKV_N + dg0 * 8;
  const short* ks1 = Kg + (size_t)kv1 * QKV_N + dg1 * 8;

  // ---- V reg-load sources (LINEAR granule: coalesced 256 B rows) and
  //      ds_write destinations (XOR'd granule -> r14-identical layout) ----
  const int vd0  = t >> 4;             // d row 0..31
  const int vd1  = vd0 + 32;
  const short* vls0 = vt_bh + (size_t)vd0 * SEQ + (t & 15) * 8;
  const short* vls1 = vt_bh + (size_t)vd1 * SEQ + (t & 15) * 8;
  short* vwd0 = VxL + vd0 * 128 + (((t & 15) ^ (vd0 & 15)) * 8);
  short* vwd1 = VxL + vd1 * 128 + (((t & 15) ^ (vd1 & 15)) * 8);
  // prologue V(0) DMA (r14-verified source permute, dest lane-linear):
  const short* vs0 = vt_bh + (size_t)vd0 * SEQ + (((t & 15) ^ (vd0 & 15)) * 8);
  const short* vs1 = vt_bh + (size_t)vd1 * SEQ + (((t & 15) ^ (vd1 & 15)) * 8);

  // ---- prologue: DMA K(0), V(0); drain at barrier ----
  __builtin_amdgcn_global_load_lds(AS1C(ks0), AS3(KxL + w * 512), 16, 0, 0);
  __builtin_amdgcn_global_load_lds(AS1C(ks1), AS3(KxL + w * 512 + 4096), 16, 0, 0);
  __builtin_amdgcn_global_load_lds(AS1C(vs0), AS3(VxL + w * 512), 16, 0, 0);
  __builtin_amdgcn_global_load_lds(AS1C(vs1), AS3(VxL + w * 512 + 4096), 16, 0, 0);
  __syncthreads();

  const int krow = kh * 32 + q31;
  const int kxor = l & 7;
  const int vx0  = q31 & 15;           // V read-side granule XOR (d & 15)

  for (int ti = 0; ti < SEQ / 128; ++ti) {
    const bool have_next = (ti + 1) < SEQ / 128;

    // ---- QK^T(ti): 4 b128 K reads + 4 MFMA ----
    f32x16 sc = {};
#pragma unroll
    for (int c16 = 0; c16 < 4; ++c16) {
      bf16x8 kb = *reinterpret_cast<const bf16x8*>(
          (const char*)KxL + krow * 128 + (((c16 * 2 + hi) ^ kxor) << 4));
      sc = __builtin_amdgcn_mfma_f32_32x32x16_bf16(kb, qf[c16], sc, 0, 0, 0);
    }
    __syncthreads();   // BAR-A: QK reads retired (Kx free); drains prior
                       //        iteration's V ds_writes (lgkmcnt, cheap)

    // ---- issue K(ti+1) DMA + V(ti+1) reg loads (both drain at BAR-B;
    //      in-flight window = softmax + PV ≈ 500 cy) ----
    bf16x8 vA, vB;
    if (have_next) {
      const size_t rb = (size_t)(ti + 1) * 128 * QKV_N;
      __builtin_amdgcn_global_load_lds(AS1C(ks0 + rb), AS3(KxL + w * 512), 16, 0, 0);
      __builtin_amdgcn_global_load_lds(AS1C(ks1 + rb), AS3(KxL + w * 512 + 4096), 16, 0, 0);
      const size_t vb = (size_t)(ti + 1) * 128;
      vA = *reinterpret_cast<const bf16x8*>(vls0 + vb);
      vB = *reinterpret_cast<const bf16x8*>(vls1 + vb);
    }

    // ---- softmax(ti) + PV(ti), P in-register (log2 domain) ----
    {
      float pm = fmaxf(fmaxf(sc[0], sc[1]), fmaxf(sc[2], sc[3]));
#pragma unroll
      for (int r = 4; r < 16; r += 4)
        pm = fmaxf(pm, fmaxf(fmaxf(sc[r], sc[r + 1]), fmaxf(sc[r + 2], sc[r + 3])));
      pm = fmaxf(pm, __shfl_xor(pm, 32));   // pair-uniform max
      if (__any(pm - mrow > 8.f)) {         // defer-max (THR=8), wave-uniform
        const float mnew = fmaxf(mrow, pm);
        const float corr = fast_exp2(mrow - mnew);
        mrow = mnew;
        lrow *= corr;
#pragma unroll
        for (int r = 0; r < 16; ++r) { o0[r] *= corr; o1[r] *= corr; }
      }
      float psum = 0.f;
#pragma unroll
      for (int c = 0; c < 2; ++c) {
        const int rr0 = c * 2, rr1 = c * 2 + 1;
        const float e0 = fast_exp2(sc[rr0 * 4 + 0] - mrow);
        const float e1 = fast_exp2(sc[rr0 * 4 + 1] - mrow);
        const float e2 = fast_exp2(sc[rr0 * 4 + 2] - mrow);
        const float e3 = fast_exp2(sc[rr0 * 4 + 3] - mrow);
        const float e4 = fast_exp2(sc[rr1 * 4 + 0] - mrow);
        const float e5 = fast_exp2(sc[rr1 * 4 + 1] - mrow);
        const float e6 = fast_exp2(sc[rr1 * 4 + 2] - mrow);
        const float e7 = fast_exp2(sc[rr1 * 4 + 3] - mrow);
        psum += ((e0 + e1) + (e2 + e3)) + ((e4 + e5) + (e6 + e7));
        const unsigned W0 = packbf(e0, e1), W1 = packbf(e2, e3);   // rr = c*2
        const unsigned W2 = packbf(e4, e5), W3 = packbf(e6, e7);   // rr = c*2+1
        // exchange: lane hi=0 sends W[c*2+1] (W2,W3), receives partner W[c*2];
        //           lane hi=1 sends W[c*2] (W0,W1), receives partner W[c*2+1].
        const unsigned s0 = hi ? W0 : W2;
        const unsigned s1 = hi ? W1 : W3;
        const unsigned r0 = __shfl_xor(s0, 32);
        const unsigned r1 = __shfl_xor(s1, 32);
        const unsigned a0 = hi ? r0 : W0;
        const unsigned a1 = hi ? r1 : W1;
        const unsigned a2 = hi ? W2 : r0;
        const unsigned a3 = hi ? W3 : r1;
        bf16x8 pb = frag_from(a0, a1, a2, a3);
        const int kvg = kh * 4 + c * 2 + hi;
        {
          bf16x8 va = *reinterpret_cast<const bf16x8*>(
              (const char*)VxL + q31 * 256 + ((kvg ^ vx0) << 4));
          o0 = __builtin_amdgcn_mfma_f32_32x32x16_bf16(va, pb, o0, 0, 0, 0);
        }
        {
          bf16x8 va = *reinterpret_cast<const bf16x8*>(
              (const char*)VxL + (32 + q31) * 256 + ((kvg ^ vx0) << 4));
          o1 = __builtin_amdgcn_mfma_f32_32x32x16_bf16(va, pb, o1, 0, 0, 0);
        }
      }
      lrow += psum;
    }
    __syncthreads();   // BAR-B: PV reads retired; drains K(ti+1) DMA and
                       //        the V(ti+1) reg loads (vmcnt(0))

    // ---- write V(ti+1) regs -> VxL (safe: PV(ti) reads retired; ordered
    //      before PV(ti+1) by BAR-A(ti+1)'s lgkmcnt) ----
    if (have_next) {
      *reinterpret_cast<bf16x8*>(vwd0) = vA;
      *reinterpret_cast<bf16x8*>(vwd1) = vB;
    }
  }

  // ---- combine the two k-half l partials (lanes l, l^32 share q) ----
  lrow += __shfl_xor(lrow, 32);

  // ---- exact flash merge of the 4 kh partials (r12-verified; log2 dom) ----
  float* mbf = (float*)smem;           // 34 f32 x 64 lanes x 4 slots = 34,816 B
  const int base = (qq * 2 + (kh >> 1)) * 2176 + l * 34;
  if (kh & 1) {                        // kh = 1,3 write
#pragma unroll
    for (int r = 0; r < 16; ++r) { mbf[base + r] = o0[r]; mbf[base + 16 + r] = o1[r]; }
    mbf[base + 32] = mrow;
    mbf[base + 33] = lrow;
  }
  __syncthreads();
  if (!(kh & 1)) {                     // kh = 0,2 merge partner kh+1
    const float m2 = mbf[base + 32];
    const float l2 = mbf[base + 33];
    const float mn = fmaxf(mrow, m2);
    const float ca = fast_exp2(mrow - mn);
    const float cb = fast_exp2(m2 - mn);
#pragma unroll
    for (int r = 0; r < 16; ++r) {
      o0[r] = o0[r] * ca + mbf[base + r] * cb;
      o1[r] = o1[r] * ca + mbf[base + 16 + r] * cb;
    }
    lrow = lrow * ca + l2 * cb;
    mrow = mn;
  }
  __syncthreads();
  const int base2 = qq * 2176 + l * 34;
  if (kh == 2) {                       // merged (2,3) -> slot qq
#pragma unroll
    for (int r = 0; r < 16; ++r) { mbf[base2 + r] = o0[r]; mbf[base2 + 16 + r] = o1[r]; }
    mbf[base2 + 32] = mrow;
    mbf[base2 + 33] = lrow;
  }
  __syncthreads();
  if (kh == 0) {                       // final merge + normalize + store
    const float m2 = mbf[base2 + 32];
    const float l2 = mbf[base2 + 33];
    const float mn = fmaxf(mrow, m2);
    const float ca = fast_exp2(mrow - mn);
    const float cb = fast_exp2(m2 - mn);
    const float lm = lrow * ca + l2 * cb;
    const float linv = 1.f / lm;
    short* orow = att + (size_t)(b * SEQ + q0 + qq * 32 + q31) * HID + h0 * HD;
#pragma unroll
    for (int rr = 0; rr < 4; ++rr) {
      short4 ov;
      ov.x = f2bf((o0[rr * 4 + 0] * ca + mbf[base2 + rr * 4 + 0] * cb) * linv);
      ov.y = f2bf((o0[rr * 4 + 1] * ca + mbf[base2 + rr * 4 + 1] * cb) * linv);
      ov.z = f2bf((o0[rr * 4 + 2] * ca + mbf[base2 + rr * 4 + 2] * cb) * linv);
      ov.w = f2bf((o0[rr * 4 + 3] * ca + mbf[base2 + rr * 4 + 3] * cb) * linv);
      *reinterpret_cast<short4*>(&orow[rr * 8 + hi * 4]) = ov;
      short4 ow;
      ow.x = f2bf((o1[rr * 4 + 0] * ca + mbf[base2 + 16 + rr * 4 + 0] * cb) * linv);
      ow.y = f2bf((o1[rr * 4 + 1] * ca + mbf[base2 + 16 + rr * 4 + 1] * cb) * linv);
      ow.z = f2bf((o1[rr * 4 + 2] * ca + mbf[base2 + 16 + rr * 4 + 2] * cb) * linv);
      ow.w = f2bf((o1[rr * 4 + 3] * ca + mbf[base2 + 16 + rr * 4 + 3] * cb) * linv);
      *reinterpret_cast<short4*>(&orow[32 + rr * 8 + hi * 4]) = ow;
    }
  }
}

// ---------------------------------------------------------------------------
extern "C" void kernel_launch(void* const* d_in, const int* in_sizes, int n_in,
                              void* d_out, int out_size, void* d_ws, size_t ws_size,
                              hipStream_t stream) {
  const float* x     = (const float*)d_in[0];  // [2,2048,768]
  const float* w_qkv = (const float*)d_in[1];  // [2304,768]
  const float* w_out = (const float*)d_in[2];  // [768,768]
  const float* b_out = (const float*)d_in[3];  // [768]
  float* out = (float*)d_out;                  // [2,2048,768]

  const int NX  = BATCH * SEQ * HID;   // 3,145,728
  const int NWQ = QKV_N * HID;         // 1,769,472
  const int NWO = HID * HID;           //   589,824

  char* ws = (char*)d_ws;
  short* xb   = (short*)ws;  ws += (size_t)NX  * 2;
  short* wqb  = (short*)ws;  ws += (size_t)NWQ * 2;
  short* wob  = (short*)ws;  ws += (size_t)NWO * 2;
  short* qkvb = (short*)ws;  ws += (size_t)BATCH * SEQ * QKV_N * 2;
  short* attb = (short*)ws;  ws += (size_t)BATCH * SEQ * HID * 2;
  short* vtg  = (short*)ws;  // [24][64][2048] bf16 = 6 MB

  cvt3_f32_bf16<<<dim3(2688), dim3(256), 0, stream>>>(x, xb, w_qkv, wqb, w_out, wob);

  // QKV projection (128x96 tiles; V written transposed directly to vtg)
  gemm_qkv<<<dim3(QKV_N / 96, (BATCH * SEQ) / 128), dim3(256), 0, stream>>>(
      xb, wqb, qkvb, vtg);

  // bf16 MFMA flash attention (in-register P; natural VGPR allocation)
  attn_mfma<<<dim3(BATCH * NH, SEQ / 64), dim3(512), 0, stream>>>(qkvb, vtg, attb);

  // out projection (64x64 tiles -> 768 blocks = 3/CU)
  gemm_nt_mfma64<<<dim3(HID / 64, (BATCH * SEQ) / 64), dim3(256), 0, stream>>>(
      attb, wob, b_out, out, BATCH * SEQ, HID, HID);
}

// Round 23
// 91.862 us; speedup vs baseline: 3.9929x; 1.0549x over previous
//
#include <hip/hip_runtime.h>
#include <hip/hip_bf16.h>
#include <cstdint>
#include <cstddef>

#define SEQ    2048
#define BATCH  2
#define HID    768
#define NH     12
#define HD     64
#define QKV_N  2304

typedef __attribute__((ext_vector_type(8))) short bf16x8;
typedef __attribute__((ext_vector_type(4))) float f32x4;
typedef __attribute__((ext_vector_type(16))) float f32x16;

#define AS1C(p) ((const __attribute__((address_space(1))) void*)(p))
#define AS3(p)  ((__attribute__((address_space(3))) void*)(p))

static __device__ __forceinline__ short f2bf(float x) {
  __hip_bfloat16 h = __float2bfloat16(x);  // RNE
  short s;
  __builtin_memcpy(&s, &h, 2);
  return s;
}
static __device__ __forceinline__ float bf2f(short s) {
  __hip_bfloat16 h;
  __builtin_memcpy(&h, &s, 2);
  return __bfloat162float(h);
}
// raw v_exp_f32 (2^x), no libm slow path, no extra mul
static __device__ __forceinline__ float fast_exp2(float x) {
  return __builtin_amdgcn_exp2f(x);
}

// ---------------------------------------------------------------------------
// Fused f32 -> bf16 conversion for the three inputs (one launch).
// ---------------------------------------------------------------------------
__global__ __launch_bounds__(256)
void cvt3_f32_bf16(const float* __restrict__ s0, short* __restrict__ d0,
                   const float* __restrict__ s1, short* __restrict__ d1,
                   const float* __restrict__ s2, short* __restrict__ d2) {
  int bid = blockIdx.x;
  const float* src;
  short* dst;
  if (bid < 1536)      { src = s0; dst = d0; }
  else if (bid < 2400) { src = s1; dst = d1; bid -= 1536; }
  else                 { src = s2; dst = d2; bid -= 2400; }
  const int i = (bid * 256 + threadIdx.x) * 8;
  const float4 a = *reinterpret_cast<const float4*>(src + i);
  const float4 b = *reinterpret_cast<const float4*>(src + i + 4);
  bf16x8 o;
  o[0] = f2bf(a.x); o[1] = f2bf(a.y); o[2] = f2bf(a.z); o[3] = f2bf(a.w);
  o[4] = f2bf(b.x); o[5] = f2bf(b.y); o[6] = f2bf(b.z); o[7] = f2bf(b.w);
  *reinterpret_cast<bf16x8*>(dst + i) = o;
}

// ---------------------------------------------------------------------------
// QKV GEMM, 128x96 tiles -> grid 24x32 = 768 blocks = EXACTLY 3/CU.
// m97 inner structure; wave sub-tile 64x48 (4x3 fragments). Tiles n0 < 1536
// (pure Q/K) write bf16 to qkvb; tiles n0 >= 1536 (pure V) write DIRECTLY
// TRANSPOSED to vtg[(b*12+h)*64+d][kv] as short4. Round-18 verified.
// ---------------------------------------------------------------------------
__global__ __launch_bounds__(256)
void gemm_qkv(const short* __restrict__ A, const short* __restrict__ B,
              short* __restrict__ C, short* __restrict__ vtg) {
  const int K = HID, N = QKV_N;
  __shared__ short As[128][64];   // 16 KB
  __shared__ short Bs[96][64];    // 12 KB

  const int t = threadIdx.x;
  const int w = t >> 6;
  const int l = t & 63;
  const int g = l >> 4;
  const int n = l & 15;

  const int m0 = blockIdx.y * 128;
  const int n0 = blockIdx.x * 96;
  const int wr = (w >> 1) * 64;
  const int wc = (w & 1) * 48;

  const int srowA = w * 32 + (l >> 3);
  const int srowB = w * 24 + (l >> 3);
  const int scol  = (l & 7) * 8;
  const short* Ag = A + (size_t)(m0 + srowA) * K + scol;
  const short* Bg = B + (size_t)(n0 + srowB) * K + scol;

  f32x4 acc[4][3] = {};

  for (int k0 = 0; k0 < K; k0 += 64) {
    __syncthreads();
#pragma unroll
    for (int it = 0; it < 4; ++it) {
      __builtin_amdgcn_global_load_lds(AS1C(Ag + (size_t)(it * 8) * K + k0),
                                       AS3(&As[w * 32 + it * 8][0]), 16, 0, 0);
    }
#pragma unroll
    for (int it = 0; it < 3; ++it) {
      __builtin_amdgcn_global_load_lds(AS1C(Bg + (size_t)(it * 8) * K + k0),
                                       AS3(&Bs[w * 24 + it * 8][0]), 16, 0, 0);
    }
    __syncthreads();

#pragma unroll
    for (int kk = 0; kk < 2; ++kk) {
      bf16x8 af[4], bfr[3];
#pragma unroll
      for (int m = 0; m < 4; ++m)
        af[m] = *reinterpret_cast<const bf16x8*>(&As[wr + m * 16 + n][kk * 32 + g * 8]);
#pragma unroll
      for (int j = 0; j < 3; ++j)
        bfr[j] = *reinterpret_cast<const bf16x8*>(&Bs[wc + j * 16 + n][kk * 32 + g * 8]);
#pragma unroll
      for (int m = 0; m < 4; ++m)
#pragma unroll
        for (int j = 0; j < 3; ++j)
          acc[m][j] = __builtin_amdgcn_mfma_f32_16x16x32_bf16(af[m], bfr[j], acc[m][j], 0, 0, 0);
    }
  }

  if (n0 < 1536) {
    // ---- Q/K region: bf16 scalar stores to qkvb ----
#pragma unroll
    for (int m = 0; m < 4; ++m) {
#pragma unroll
      for (int r = 0; r < 4; ++r) {
        const size_t row = m0 + wr + m * 16 + g * 4 + r;
#pragma unroll
        for (int j = 0; j < 3; ++j) {
          const int col = n0 + wc + j * 16 + n;
          C[row * N + col] = f2bf(acc[m][j][r]);
        }
      }
    }
  } else {
    // ---- V region: write transposed directly into vtg ----
    const int b = m0 >> 11;              // batch (uniform per tile)
#pragma unroll
    for (int m = 0; m < 4; ++m) {
      const int kvbase = (m0 & 2047) + wr + m * 16 + g * 4;   // % 4 == 0
#pragma unroll
      for (int j = 0; j < 3; ++j) {
        const int col2 = n0 - 1536 + wc + j * 16 + n;
        const int h = col2 >> 6;
        const int d = col2 & 63;
        short4 pk;
        pk.x = f2bf(acc[m][j][0]);
        pk.y = f2bf(acc[m][j][1]);
        pk.z = f2bf(acc[m][j][2]);
        pk.w = f2bf(acc[m][j][3]);
        *reinterpret_cast<short4*>(
            &vtg[(((size_t)b * NH + h) * 64 + d) * SEQ + kvbase]) = pk;
      }
    }
  }
}

// ---------------------------------------------------------------------------
// bf16 MFMA GEMM NT, 64x64 tile — out-proj (768 blocks = 3/CU). Known-good.
// ---------------------------------------------------------------------------
__global__ __launch_bounds__(256)
void gemm_nt_mfma64(const short* __restrict__ A, const short* __restrict__ B,
                    const float* __restrict__ bias, float* __restrict__ Cf,
                    int M, int N, int K) {
  __shared__ short As[64][64];
  __shared__ short Bs[64][64];

  const int t = threadIdx.x;
  const int w = t >> 6;
  const int l = t & 63;
  const int g = l >> 4;
  const int n = l & 15;

  const int m0 = blockIdx.y * 64;
  const int n0 = blockIdx.x * 64;
  const int wr = (w >> 1) * 32;
  const int wc = (w & 1) * 32;

  const int srow = t >> 3;
  const int scol = (t & 7) * 8;
  const short* Ag = A + (size_t)(m0 + srow) * K + scol;
  const short* Bg = B + (size_t)(n0 + srow) * K + scol;

  f32x4 acc[2][2] = {};

  for (int k0 = 0; k0 < K; k0 += 64) {
    __syncthreads();
#pragma unroll
    for (int it = 0; it < 2; ++it) {
      __builtin_amdgcn_global_load_lds(AS1C(Ag + (size_t)(it * 32) * K + k0),
                                       AS3(&As[w * 8 + it * 32][0]), 16, 0, 0);
    }
#pragma unroll
    for (int it = 0; it < 2; ++it) {
      __builtin_amdgcn_global_load_lds(AS1C(Bg + (size_t)(it * 32) * K + k0),
                                       AS3(&Bs[w * 8 + it * 32][0]), 16, 0, 0);
    }
    __syncthreads();

#pragma unroll
    for (int kk = 0; kk < 2; ++kk) {
      bf16x8 af[2], bfr[2];
#pragma unroll
      for (int m = 0; m < 2; ++m)
        af[m] = *reinterpret_cast<const bf16x8*>(&As[wr + m * 16 + n][kk * 32 + g * 8]);
#pragma unroll
      for (int j = 0; j < 2; ++j)
        bfr[j] = *reinterpret_cast<const bf16x8*>(&Bs[wc + j * 16 + n][kk * 32 + g * 8]);
#pragma unroll
      for (int m = 0; m < 2; ++m)
#pragma unroll
        for (int j = 0; j < 2; ++j)
          acc[m][j] = __builtin_amdgcn_mfma_f32_16x16x32_bf16(af[m], bfr[j], acc[m][j], 0, 0, 0);
    }
  }

#pragma unroll
  for (int m = 0; m < 2; ++m) {
#pragma unroll
    for (int r = 0; r < 4; ++r) {
      const size_t row = m0 + wr + m * 16 + g * 4 + r;
#pragma unroll
      for (int j = 0; j < 2; ++j) {
        const int col = n0 + wc + j * 16 + n;
        Cf[row * N + col] = acc[m][j][r] + bias[col];
      }
    }
  }
}

// ---------------------------------------------------------------------------
// Flash attention, 32x32x16 MFMA — round-18/20 verified best (52.6 us):
// K DMA linear+XOR, V reg-staged long-window into swizzled VxL, Ps LDS
// stride-40, exp2-builtin softmax. The r21/r22 in-register-P variant was
// A/B'd and is SLOWER (+5.1 us: shuffle+pack VALU cost > Ps LDS cost);
// setprio also A/B'd negative (-1.4 us, barrier-lockstep waves).
// ---------------------------------------------------------------------------
__global__ __launch_bounds__(512)
void attn_mfma(const short* __restrict__ qkv, const short* __restrict__ vtg,
               short* __restrict__ att) {
  const int bh = blockIdx.x;           // 0..23
  const int qt = blockIdx.y;           // 0..31
  const int b  = bh / NH;
  const int h0 = bh % NH;
  const int q0 = qt * 64;

  const int t   = threadIdx.x;
  const int w   = t >> 6;              // wave 0..7
  const int l   = t & 63;
  const int hi  = l >> 5;              // k-half
  const int q31 = l & 31;              // q column owned by this lane
  const int qq  = w >> 2;              // q 32-row group
  const int kh  = w & 3;               // kv quarter

  __shared__ __align__(16) char smem[53248];
  short* KxL = (short*)smem;            // [128][64] linear, 16384 B
  short* VxL = (short*)(smem + 16384);  // [64][128] swizzled, 16384 B
  short* PsL = (short*)(smem + 32768);  // [8][32][40], 20480 B

  const short* baseq = qkv + (size_t)b * SEQ * QKV_N + h0 * HD;
  const short* Kg    = baseq + HID;
  const short* vt_bh = vtg + (size_t)bh * 64 * SEQ;

  // ---- Q B-fragments, pre-scaled by 0.125 * log2(e) (scores in log2) ----
  bf16x8 qf[4];
  {
    const short* qrow = baseq + (size_t)(q0 + qq * 32 + q31) * QKV_N;
#pragma unroll
    for (int c16 = 0; c16 < 4; ++c16) {
      bf16x8 raw = *reinterpret_cast<const bf16x8*>(qrow + c16 * 16 + hi * 8);
#pragma unroll
      for (int j = 0; j < 8; ++j)
        qf[c16][j] = f2bf(bf2f(raw[j]) * 0.1803368801f);
    }
  }

  f32x16 o0 = {};
  f32x16 o1 = {};
  float mrow = -3e38f;
  float lrow = 0.f;

  // ---- K DMA source indices (per thread, 2 instrs; r9-verified) ----
  const int kv0  = t >> 3;
  const int dg0  = (t & 7) ^ (kv0 & 7);
  const int kv1  = kv0 + 64;
  const int dg1  = (t & 7) ^ (kv1 & 7);
  const short* ks0 = Kg + (size_t)kv0 * QKV_N + dg0 * 8;
  const short* ks1 = Kg + (size_t)kv1 * QKV_N + dg1 * 8;

  // ---- V reg-load sources (LINEAR granule: coalesced 256 B rows) and
  //      ds_write destinations (XOR'd granule -> r14-identical layout) ----
  const int vd0  = t >> 4;             // d row 0..31
  const int vd1  = vd0 + 32;
  const short* vls0 = vt_bh + (size_t)vd0 * SEQ + (t & 15) * 8;
  const short* vls1 = vt_bh + (size_t)vd1 * SEQ + (t & 15) * 8;
  short* vwd0 = VxL + vd0 * 128 + (((t & 15) ^ (vd0 & 15)) * 8);
  short* vwd1 = VxL + vd1 * 128 + (((t & 15) ^ (vd1 & 15)) * 8);
  // prologue V(0) DMA (r14-verified source permute, dest lane-linear):
  const short* vs0 = vt_bh + (size_t)vd0 * SEQ + (((t & 15) ^ (vd0 & 15)) * 8);
  const short* vs1 = vt_bh + (size_t)vd1 * SEQ + (((t & 15) ^ (vd1 & 15)) * 8);

  // ---- prologue: DMA K(0), V(0); drain at barrier ----
  __builtin_amdgcn_global_load_lds(AS1C(ks0), AS3(KxL + w * 512), 16, 0, 0);
  __builtin_amdgcn_global_load_lds(AS1C(ks1), AS3(KxL + w * 512 + 4096), 16, 0, 0);
  __builtin_amdgcn_global_load_lds(AS1C(vs0), AS3(VxL + w * 512), 16, 0, 0);
  __builtin_amdgcn_global_load_lds(AS1C(vs1), AS3(VxL + w * 512 + 4096), 16, 0, 0);
  __syncthreads();

  const int krow = kh * 32 + q31;
  const int kxor = l & 7;
  const int vx0  = q31 & 15;           // V read-side granule XOR (d & 15)

  for (int ti = 0; ti < SEQ / 128; ++ti) {
    const bool have_next = (ti + 1) < SEQ / 128;

    // ---- QK^T(ti): 4 b128 K reads + 4 MFMA ----
    f32x16 sc = {};
#pragma unroll
    for (int c16 = 0; c16 < 4; ++c16) {
      bf16x8 kb = *reinterpret_cast<const bf16x8*>(
          (const char*)KxL + krow * 128 + (((c16 * 2 + hi) ^ kxor) << 4));
      sc = __builtin_amdgcn_mfma_f32_32x32x16_bf16(kb, qf[c16], sc, 0, 0, 0);
    }
    __syncthreads();   // BAR-A: QK reads retired (Kx free); drains prior
                       //        iteration's V ds_writes (lgkmcnt, cheap)

    // ---- issue K(ti+1) DMA + V(ti+1) reg loads (both drain at BAR-B;
    //      in-flight window = softmax + PV ≈ 500 cy) ----
    bf16x8 vA, vB;
    if (have_next) {
      const size_t rb = (size_t)(ti + 1) * 128 * QKV_N;
      __builtin_amdgcn_global_load_lds(AS1C(ks0 + rb), AS3(KxL + w * 512), 16, 0, 0);
      __builtin_amdgcn_global_load_lds(AS1C(ks1 + rb), AS3(KxL + w * 512 + 4096), 16, 0, 0);
      const size_t vb = (size_t)(ti + 1) * 128;
      vA = *reinterpret_cast<const bf16x8*>(vls0 + vb);
      vB = *reinterpret_cast<const bf16x8*>(vls1 + vb);
    }

    // ---- softmax(ti), log2 domain: lane owns 16 of 32 kv rows, q = q31 ----
    {
      float pm = fmaxf(fmaxf(sc[0], sc[1]), fmaxf(sc[2], sc[3]));
#pragma unroll
      for (int r = 4; r < 16; r += 4)
        pm = fmaxf(pm, fmaxf(fmaxf(sc[r], sc[r + 1]), fmaxf(sc[r + 2], sc[r + 3])));
      pm = fmaxf(pm, __shfl_xor(pm, 32));
      if (__any(pm - mrow > 8.f)) {     // defer-max (THR=8 in log2 domain)
        const float mnew = fmaxf(mrow, pm);
        const float corr = fast_exp2(mrow - mnew);
        mrow = mnew;
        lrow *= corr;
#pragma unroll
        for (int r = 0; r < 16; ++r) { o0[r] *= corr; o1[r] *= corr; }
      }
      float psum = 0.f;
#pragma unroll
      for (int rr = 0; rr < 4; ++rr) {
        const float p0 = fast_exp2(sc[rr * 4 + 0] - mrow);
        const float p1 = fast_exp2(sc[rr * 4 + 1] - mrow);
        const float p2 = fast_exp2(sc[rr * 4 + 2] - mrow);
        const float p3 = fast_exp2(sc[rr * 4 + 3] - mrow);
        psum += (p0 + p1) + (p2 + p3);
        short4 pk;
        pk.x = f2bf(p0); pk.y = f2bf(p1); pk.z = f2bf(p2); pk.w = f2bf(p3);
        *reinterpret_cast<short4*>(
            &PsL[w * 1280 + q31 * 40 + rr * 8 + hi * 4]) = pk;
      }
      lrow += psum;
    }
    // Ps wave-local: ds_write -> ds_read ordered by lgkmcnt.

    // ---- PV(ti): V frags from VxL (XOR-matched b128) + Ps reads + 4 MFMA ----
#pragma unroll
    for (int c = 0; c < 2; ++c) {
      bf16x8 pb = *reinterpret_cast<const bf16x8*>(
          &PsL[w * 1280 + q31 * 40 + c * 16 + hi * 8]);
      const int kvg = kh * 4 + c * 2 + hi;
      {
        bf16x8 va = *reinterpret_cast<const bf16x8*>(
            (const char*)VxL + q31 * 256 + ((kvg ^ vx0) << 4));
        o0 = __builtin_amdgcn_mfma_f32_32x32x16_bf16(va, pb, o0, 0, 0, 0);
      }
      {
        bf16x8 va = *reinterpret_cast<const bf16x8*>(
            (const char*)VxL + (32 + q31) * 256 + ((kvg ^ vx0) << 4));
        o1 = __builtin_amdgcn_mfma_f32_32x32x16_bf16(va, pb, o1, 0, 0, 0);
      }
    }
    __syncthreads();   // BAR-B: PV reads retired; drains K(ti+1) DMA and
                       //        the V(ti+1) reg loads (vmcnt(0))

    // ---- write V(ti+1) regs -> VxL (safe: PV(ti) reads retired; ordered
    //      before PV(ti+1) by BAR-A(ti+1)'s lgkmcnt) ----
    if (have_next) {
      *reinterpret_cast<bf16x8*>(vwd0) = vA;
      *reinterpret_cast<bf16x8*>(vwd1) = vB;
    }
  }

  // ---- combine the two k-half l partials (lanes l, l^32 share q) ----
  lrow += __shfl_xor(lrow, 32);

  // ---- exact flash merge of the 4 kh partials (r12-verified; log2 dom) ----
  float* mbf = (float*)smem;           // 34 f32 x 64 lanes x 4 slots = 34,816 B
  const int base = (qq * 2 + (kh >> 1)) * 2176 + l * 34;
  if (kh & 1) {                        // kh = 1,3 write
#pragma unroll
    for (int r = 0; r < 16; ++r) { mbf[base + r] = o0[r]; mbf[base + 16 + r] = o1[r]; }
    mbf[base + 32] = mrow;
    mbf[base + 33] = lrow;
  }
  __syncthreads();
  if (!(kh & 1)) {                     // kh = 0,2 merge partner kh+1
    const float m2 = mbf[base + 32];
    const float l2 = mbf[base + 33];
    const float mn = fmaxf(mrow, m2);
    const float ca = fast_exp2(mrow - mn);
    const float cb = fast_exp2(m2 - mn);
#pragma unroll
    for (int r = 0; r < 16; ++r) {
      o0[r] = o0[r] * ca + mbf[base + r] * cb;
      o1[r] = o1[r] * ca + mbf[base + 16 + r] * cb;
    }
    lrow = lrow * ca + l2 * cb;
    mrow = mn;
  }
  __syncthreads();
  const int base2 = qq * 2176 + l * 34;
  if (kh == 2) {                       // merged (2,3) -> slot qq
#pragma unroll
    for (int r = 0; r < 16; ++r) { mbf[base2 + r] = o0[r]; mbf[base2 + 16 + r] = o1[r]; }
    mbf[base2 + 32] = mrow;
    mbf[base2 + 33] = lrow;
  }
  __syncthreads();
  if (kh == 0) {                       // final merge + normalize + store
    const float m2 = mbf[base2 + 32];
    const float l2 = mbf[base2 + 33];
    const float mn = fmaxf(mrow, m2);
    const float ca = fast_exp2(mrow - mn);
    const float cb = fast_exp2(m2 - mn);
    const float lm = lrow * ca + l2 * cb;
    const float linv = 1.f / lm;
    short* orow = att + (size_t)(b * SEQ + q0 + qq * 32 + q31) * HID + h0 * HD;
#pragma unroll
    for (int rr = 0; rr < 4; ++rr) {
      short4 ov;
      ov.x = f2bf((o0[rr * 4 + 0] * ca + mbf[base2 + rr * 4 + 0] * cb) * linv);
      ov.y = f2bf((o0[rr * 4 + 1] * ca + mbf[base2 + rr * 4 + 1] * cb) * linv);
      ov.z = f2bf((o0[rr * 4 + 2] * ca + mbf[base2 + rr * 4 + 2] * cb) * linv);
      ov.w = f2bf((o0[rr * 4 + 3] * ca + mbf[base2 + rr * 4 + 3] * cb) * linv);
      *reinterpret_cast<short4*>(&orow[rr * 8 + hi * 4]) = ov;
      short4 ow;
      ow.x = f2bf((o1[rr * 4 + 0] * ca + mbf[base2 + 16 + rr * 4 + 0] * cb) * linv);
      ow.y = f2bf((o1[rr * 4 + 1] * ca + mbf[base2 + 16 + rr * 4 + 1] * cb) * linv);
      ow.z = f2bf((o1[rr * 4 + 2] * ca + mbf[base2 + 16 + rr * 4 + 2] * cb) * linv);
      ow.w = f2bf((o1[rr * 4 + 3] * ca + mbf[base2 + 16 + rr * 4 + 3] * cb) * linv);
      *reinterpret_cast<short4*>(&orow[32 + rr * 8 + hi * 4]) = ow;
    }
  }
}

// ---------------------------------------------------------------------------
extern "C" void kernel_launch(void* const* d_in, const int* in_sizes, int n_in,
                              void* d_out, int out_size, void* d_ws, size_t ws_size,
                              hipStream_t stream) {
  const float* x     = (const float*)d_in[0];  // [2,2048,768]
  const float* w_qkv = (const float*)d_in[1];  // [2304,768]
  const float* w_out = (const float*)d_in[2];  // [768,768]
  const float* b_out = (const float*)d_in[3];  // [768]
  float* out = (float*)d_out;                  // [2,2048,768]

  const int NX  = BATCH * SEQ * HID;   // 3,145,728
  const int NWQ = QKV_N * HID;         // 1,769,472
  const int NWO = HID * HID;           //   589,824

  char* ws = (char*)d_ws;
  short* xb   = (short*)ws;  ws += (size_t)NX  * 2;
  short* wqb  = (short*)ws;  ws += (size_t)NWQ * 2;
  short* wob  = (short*)ws;  ws += (size_t)NWO * 2;
  short* qkvb = (short*)ws;  ws += (size_t)BATCH * SEQ * QKV_N * 2;
  short* attb = (short*)ws;  ws += (size_t)BATCH * SEQ * HID * 2;
  short* vtg  = (short*)ws;  // [24][64][2048] bf16 = 6 MB

  cvt3_f32_bf16<<<dim3(2688), dim3(256), 0, stream>>>(x, xb, w_qkv, wqb, w_out, wob);

  // QKV projection (128x96 tiles; V written transposed directly to vtg)
  gemm_qkv<<<dim3(QKV_N / 96, (BATCH * SEQ) / 128), dim3(256), 0, stream>>>(
      xb, wqb, qkvb, vtg);

  // bf16 MFMA flash attention (r18/r20 verified best) -> attb
  attn_mfma<<<dim3(BATCH * NH, SEQ / 64), dim3(512), 0, stream>>>(qkvb, vtg, attb);

  // out projection (64x64 tiles -> 768 blocks = 3/CU)
  gemm_nt_mfma64<<<dim3(HID / 64, (BATCH * SEQ) / 64), dim3(256), 0, stream>>>(
      attb, wob, b_out, out, BATCH * SEQ, HID, HID);
}